// Round 2
// baseline (427.376 us; speedup 1.0000x reference)
//
#include <hip/hip_runtime.h>
#include <hip/hip_bf16.h>

#define D 64
#define NUM_LAYERS 4
#define TILE 4096
#define EPT 16          // edges per thread in placeA (256 thr * 16 = TILE)
#define BKMAX 320       // max buckets (N <= 163840)

// ---------------- bucket histogram + scan ----------------

__global__ void bhist_kernel(const int* __restrict__ dst, int* __restrict__ bcnt, int E, int nbk) {
    __shared__ int h[BKMAX];
    for (int i = threadIdx.x; i < nbk; i += blockDim.x) h[i] = 0;
    __syncthreads();
    int stride = gridDim.x * blockDim.x;
    for (int e = blockIdx.x * blockDim.x + threadIdx.x; e < E; e += stride)
        atomicAdd(&h[dst[e] >> 9], 1);
    __syncthreads();
    for (int i = threadIdx.x; i < nbk; i += blockDim.x)
        if (h[i] > 0) atomicAdd(&bcnt[i], h[i]);
}

// single block: exclusive scan of bucket counts -> bstart, gcur
__global__ __launch_bounds__(512) void bscan_kernel(const int* __restrict__ bcnt,
                                                    int* __restrict__ bstart,
                                                    int* __restrict__ gcur, int nbk, int E) {
    __shared__ int sm[512];
    int t = threadIdx.x;
    int v = (t < nbk) ? bcnt[t] : 0;
    sm[t] = v;
    __syncthreads();
    for (int ofs = 1; ofs < 512; ofs <<= 1) {
        int x = (t >= ofs) ? sm[t - ofs] : 0;
        __syncthreads();
        sm[t] += x;
        __syncthreads();
    }
    int excl = sm[t] - v;
    if (t < nbk) { bstart[t] = excl; gcur[t] = excl; }
    if (t == 0) bstart[nbk] = E;
}

// ---------------- place: two-phase tile-partitioned counting sort ----------------

// Pass A: tile -> bucket-sorted mid. Payload: src | (dst&511)<<18  (27 bits, 4B)
__global__ __launch_bounds__(256) void placeA_kernel(const int* __restrict__ src,
                                                     const int* __restrict__ dst,
                                                     int* __restrict__ gcur,
                                                     int* __restrict__ mid,
                                                     int E, int nbk) {
    __shared__ int hist[BKMAX];
    __shared__ int gbase[BKMAX];
    int t = threadIdx.x;
    int tile0 = blockIdx.x * TILE;
    for (int i = t; i < nbk; i += 256) hist[i] = 0;
    __syncthreads();

    int p_[EPT];
    int b_[EPT];
    int r_[EPT];
#pragma unroll
    for (int i = 0; i < EPT; ++i) {
        int e = tile0 + i * 256 + t;
        b_[i] = -1;
        if (e < E) {
            int s = src[e], d = dst[e];
            p_[i] = s | ((d & 511) << 18);
            b_[i] = d >> 9;
            r_[i] = atomicAdd(&hist[b_[i]], 1);
        }
    }
    __syncthreads();
    for (int b = t; b < nbk; b += 256) {
        int h = hist[b];
        gbase[b] = (h > 0) ? atomicAdd(&gcur[b], h) : 0;
    }
    __syncthreads();
#pragma unroll
    for (int i = 0; i < EPT; ++i) {
        if (b_[i] >= 0) mid[gbase[b_[i]] + r_[i]] = p_[i];
    }
}

// Pass B1: one block per bucket; per-node degree count in LDS, LDS scan ->
// row_start + deg_inv_sqrt for this bucket's 512 nodes.
__global__ __launch_bounds__(512) void placeB1_kernel(const int* __restrict__ bstart,
                                                      const int* __restrict__ mid,
                                                      int* __restrict__ row_start,
                                                      float* __restrict__ dis,
                                                      int N, int nbk, int E) {
    __shared__ int degsm[512];
    __shared__ int sc[512];
    int b = blockIdx.x;
    int t = threadIdx.x;
    int node0 = b << 9;
    int lo = bstart[b], hi = bstart[b + 1];
    degsm[t] = 0;
    __syncthreads();
    for (int e = lo + t; e < hi; e += 512)
        atomicAdd(&degsm[(mid[e] >> 18) & 511], 1);
    __syncthreads();
    int d = degsm[t];
    sc[t] = d;
    __syncthreads();
    for (int ofs = 1; ofs < 512; ofs <<= 1) {
        int x = (t >= ofs) ? sc[t - ofs] : 0;
        __syncthreads();
        sc[t] += x;
        __syncthreads();
    }
    int excl = sc[t] - d;
    int node = node0 + t;
    if (node < N) {
        row_start[node] = lo + excl;
        dis[node] = (d > 0) ? rsqrtf((float)d) : 0.0f;
    }
    if (b == nbk - 1 && t == 0) row_start[N] = E;
}

// Pass B2: scatter within bucket; compute w = dis[src]*dis[dst] once here.
__global__ __launch_bounds__(512) void placeB2_kernel(const int* __restrict__ bstart,
                                                      const int* __restrict__ mid,
                                                      const int* __restrict__ row_start,
                                                      const float* __restrict__ dis,
                                                      int2* __restrict__ csr, int N) {
    __shared__ int cur[512];
    __shared__ float dloc[512];
    int b = blockIdx.x;
    int t = threadIdx.x;
    int node0 = b << 9;
    int node = node0 + t;
    if (node < N) { cur[t] = row_start[node]; dloc[t] = dis[node]; }
    else          { cur[t] = 0; dloc[t] = 0.0f; }
    __syncthreads();
    int lo = bstart[b], hi = bstart[b + 1];
    for (int e = lo + t; e < hi; e += 512) {
        int m = mid[e];
        int l = (m >> 18) & 511;
        int s = m & 0x3FFFF;
        float w = dis[s] * dloc[l];
        int slot = atomicAdd(&cur[l], 1);
        csr[slot] = make_int2(s, __float_as_int(w));
    }
}

// ---------------- propagation ----------------

__global__ void init_kernel(const float* __restrict__ users, const float* __restrict__ items,
                            unsigned* __restrict__ A, int nu_elems, int total2) {
    int i = blockIdx.x * blockDim.x + threadIdx.x;   // bf16x2 pair index
    if (i >= total2) return;
    int base = i * 2;
    float2 v;
    if (base < nu_elems) v = ((const float2*)users)[i];
    else                 v = ((const float2*)items)[(base - nu_elems) >> 1];
    __hip_bfloat16 bx = __float2bfloat16(v.x);
    __hip_bfloat16 by = __float2bfloat16(v.y);
    unsigned p = (unsigned)(*reinterpret_cast<unsigned short*>(&bx))
               | ((unsigned)(*reinterpret_cast<unsigned short*>(&by)) << 16);
    A[i] = p;
}

__device__ __forceinline__ float bf_lo(unsigned u) { return __uint_as_float(u << 16); }
__device__ __forceinline__ float bf_hi(unsigned u) { return __uint_as_float(u & 0xffff0000u); }
__device__ __forceinline__ unsigned bf_pack(float x, float y) {
    __hip_bfloat16 bx = __float2bfloat16(x);
    __hip_bfloat16 by = __float2bfloat16(y);
    return (unsigned)(*reinterpret_cast<unsigned short*>(&bx))
         | ((unsigned)(*reinterpret_cast<unsigned short*>(&by)) << 16);
}

// One QUARTER-WAVE (16 lanes) per dst node: c = lane&15 picks the bf16x4 (8B)
// chunk of the 128B row. Each quarter walks its node's edge list with a masked
// 4-deep unroll: 4 independent csr loads (same-addr across the 16 lanes ->
// single request) feeding 4 independent 128B row gathers -> ~32 loads in
// flight per wave (vs ~2-4 in the wave-per-node + shfl version). No cross-lane
// reduction needed; 4 consecutive nodes per wave -> coalesced stores.
template <int FINAL>
__global__ __launch_bounds__(256) void gather_kernel(const int* __restrict__ row_start,
                              const int2* __restrict__ csr,
                              const uint2* __restrict__ Au,
                              uint2* __restrict__ Bu,
                              const float* __restrict__ users, const float* __restrict__ items,
                              const uint2* __restrict__ L1u, const uint2* __restrict__ L2u,
                              float* __restrict__ out,
                              int N, int nu) {
    int node = (blockIdx.x * blockDim.x + threadIdx.x) >> 4;
    if (node >= N) return;
    int c = threadIdx.x & 15;
    int beg = row_start[node];
    int end = row_start[node + 1];

    const long long* csr64 = (const long long*)csr;

    // independent accumulators per unroll slot (no FMA dep chain)
    float ax0 = 0.f, ay0 = 0.f, az0 = 0.f, aw0 = 0.f;
    float ax1 = 0.f, ay1 = 0.f, az1 = 0.f, aw1 = 0.f;
    float ax2 = 0.f, ay2 = 0.f, az2 = 0.f, aw2 = 0.f;
    float ax3 = 0.f, ay3 = 0.f, az3 = 0.f, aw3 = 0.f;

    for (int j = beg; j < end; j += 4) {
        int last = end - 1;
        int j1 = min(j + 1, last);
        int j2 = min(j + 2, last);
        int j3 = min(j + 3, last);
        long long p0 = __builtin_nontemporal_load(csr64 + j);
        long long p1 = __builtin_nontemporal_load(csr64 + j1);
        long long p2 = __builtin_nontemporal_load(csr64 + j2);
        long long p3 = __builtin_nontemporal_load(csr64 + j3);
        int s0 = (int)(p0 & 0xFFFFFFFFLL);
        int s1 = (int)(p1 & 0xFFFFFFFFLL);
        int s2 = (int)(p2 & 0xFFFFFFFFLL);
        int s3 = (int)(p3 & 0xFFFFFFFFLL);
        uint2 u0 = Au[(size_t)s0 * 16 + c];
        uint2 u1 = Au[(size_t)s1 * 16 + c];
        uint2 u2 = Au[(size_t)s2 * 16 + c];
        uint2 u3 = Au[(size_t)s3 * 16 + c];
        float w0 = __int_as_float((int)(p0 >> 32));
        float w1 = (j + 1 < end) ? __int_as_float((int)(p1 >> 32)) : 0.0f;
        float w2 = (j + 2 < end) ? __int_as_float((int)(p2 >> 32)) : 0.0f;
        float w3 = (j + 3 < end) ? __int_as_float((int)(p3 >> 32)) : 0.0f;
        ax0 += w0 * bf_lo(u0.x); ay0 += w0 * bf_hi(u0.x);
        az0 += w0 * bf_lo(u0.y); aw0 += w0 * bf_hi(u0.y);
        ax1 += w1 * bf_lo(u1.x); ay1 += w1 * bf_hi(u1.x);
        az1 += w1 * bf_lo(u1.y); aw1 += w1 * bf_hi(u1.y);
        ax2 += w2 * bf_lo(u2.x); ay2 += w2 * bf_hi(u2.x);
        az2 += w2 * bf_lo(u2.y); aw2 += w2 * bf_hi(u2.y);
        ax3 += w3 * bf_lo(u3.x); ay3 += w3 * bf_hi(u3.x);
        az3 += w3 * bf_lo(u3.y); aw3 += w3 * bf_hi(u3.y);
    }

    float ax = (ax0 + ax1) + (ax2 + ax3);
    float ay = (ay0 + ay1) + (ay2 + ay3);
    float az = (az0 + az1) + (az2 + az3);
    float aw = (aw0 + aw1) + (aw2 + aw3);

    size_t ro = (size_t)node * 16 + c;
    if (FINAL) {
        uint2 l1;
        l1.x = __builtin_nontemporal_load(&L1u[ro].x);
        l1.y = __builtin_nontemporal_load(&L1u[ro].y);
        uint2 l2;
        l2.x = __builtin_nontemporal_load(&L2u[ro].x);
        l2.y = __builtin_nontemporal_load(&L2u[ro].y);
        uint2 l3 = Au[ro];
        float4 e0;
        if (node < nu) e0 = ((const float4*)users)[ro];
        else           e0 = ((const float4*)items)[(size_t)(node - nu) * 16 + c];
        float rx = (e0.x + bf_lo(l1.x) + bf_lo(l2.x) + bf_lo(l3.x) + ax) * 0.04f;
        float ry = (e0.y + bf_hi(l1.x) + bf_hi(l2.x) + bf_hi(l3.x) + ay) * 0.04f;
        float rz = (e0.z + bf_lo(l1.y) + bf_lo(l2.y) + bf_lo(l3.y) + az) * 0.04f;
        float rw = (e0.w + bf_hi(l1.y) + bf_hi(l2.y) + bf_hi(l3.y) + aw) * 0.04f;
        ((float4*)out)[ro] = make_float4(rx, ry, rz, rw);
    } else {
        uint2 p;
        p.x = bf_pack(ax, ay);
        p.y = bf_pack(az, aw);
        Bu[ro] = p;
    }
}

// ---------------- launch ----------------

extern "C" void kernel_launch(void* const* d_in, const int* in_sizes, int n_in,
                              void* d_out, int out_size, void* d_ws, size_t ws_size,
                              hipStream_t stream) {
    const float* users = (const float*)d_in[0];
    const float* items = (const float*)d_in[1];
    const int*   eidx  = (const int*)d_in[2];

    const int nu = in_sizes[0] / D;    // 100000
    const int ni = in_sizes[1] / D;    // 50000
    const int N  = nu + ni;            // 150000
    const int E  = in_sizes[2] / 2;    // 2000000
    const int Nf = N * D;              // 9.6M elems
    const int nbk = (N + 511) >> 9;    // 293 buckets

    const int* src = eidx;
    const int* dst = eidx + E;

    char* ws = (char*)d_ws;
    size_t off = 0;
    auto alloc = [&](size_t bytes) {
        char* p = ws + off;
        off += (bytes + 255) & ~(size_t)255;
        return p;
    };
    float* dis       = (float*)alloc((size_t)N * 4);
    int*   row_start = (int*)alloc((size_t)(N + 1) * 4);
    int*   bcnt      = (int*)alloc(BKMAX * 4);
    int*   bstart    = (int*)alloc((BKMAX + 1) * 4);
    int*   gcur      = (int*)alloc(BKMAX * 4);
    int2*  csr       = (int2*)alloc((size_t)E * 8);
    unsigned* A0 = (unsigned*)alloc((size_t)Nf * 2);
    unsigned* L1 = (unsigned*)alloc((size_t)Nf * 2);
    unsigned* L2 = (unsigned*)alloc((size_t)Nf * 2);
    unsigned* L3 = (unsigned*)alloc((size_t)Nf * 2);
    int* mid = (int*)L3;   // alias: mid (E*4B) consumed before L3 is written (gather #3)

    const int B256 = 256;
    auto blocks = [](long long n, int b) { return (int)((n + b - 1) / b); };

    // 1. bucket histogram + bucket scan
    hipMemsetAsync(bcnt, 0, BKMAX * 4, stream);
    bhist_kernel<<<1024, B256, 0, stream>>>(dst, bcnt, E, nbk);
    bscan_kernel<<<1, 512, 0, stream>>>(bcnt, bstart, gcur, nbk, E);

    // 2. place: tile-partition into buckets (4B payload), then per-bucket
    //    degree count + scan (B1) and weighted scatter (B2)
    placeA_kernel<<<blocks(E, TILE), B256, 0, stream>>>(src, dst, gcur, mid, E, nbk);
    placeB1_kernel<<<nbk, 512, 0, stream>>>(bstart, mid, row_start, dis, N, nbk, E);
    placeB2_kernel<<<nbk, 512, 0, stream>>>(bstart, mid, row_start, dis, csr, N);

    // 3. init bf16 A0
    init_kernel<<<blocks(Nf / 2, B256), B256, 0, stream>>>(users, items, A0, nu * D, Nf / 2);

    // 4. propagation: quarter-wave per node; L1..L3 bf16; layer 4 fused with
    //    final combine -> f32 d_out
    const int ggrid = blocks((long long)N * 16, B256);
    gather_kernel<0><<<ggrid, B256, 0, stream>>>(row_start, csr, (const uint2*)A0, (uint2*)L1,
                                                 nullptr, nullptr, nullptr, nullptr, nullptr, N, nu);
    gather_kernel<0><<<ggrid, B256, 0, stream>>>(row_start, csr, (const uint2*)L1, (uint2*)L2,
                                                 nullptr, nullptr, nullptr, nullptr, nullptr, N, nu);
    gather_kernel<0><<<ggrid, B256, 0, stream>>>(row_start, csr, (const uint2*)L2, (uint2*)L3,
                                                 nullptr, nullptr, nullptr, nullptr, nullptr, N, nu);
    gather_kernel<1><<<ggrid, B256, 0, stream>>>(row_start, csr, (const uint2*)L3, nullptr,
                                                 users, items, (const uint2*)L1, (const uint2*)L2,
                                                 (float*)d_out, N, nu);
}